// Round 3
// baseline (269.380 us; speedup 1.0000x reference)
//
#include <hip/hip_runtime.h>
#include <math.h>

#define H 4096
#define NIN 17
#define H4 (H / 4)                    // 1024
#define NSPLIT 512
#define ROWS_PER_SPLIT (H / NSPLIT)   // 8
#define NSPLIT2 32                    // second-stage split count (512/16)

typedef float vf4 __attribute__((ext_vector_type(4)));

// d_out layout (fp32): [activout(4), valueout(1), hactiv(4096), hebb_new(4096*4096)]
//   hactiv at element offset 5; hebb at element offset 4101 (4B aligned only).
// Scratch lives inside the hebb output region (overwritten by kC afterwards):
//   partial  at 4104 (byte 16416, 16B aligned): NSPLIT  x H floats (8 MB)
//   partial2 at 4104 + NSPLIT*H: NSPLIT2 x H floats
#define OUT_HACTIV_OFF  5
#define OUT_HEBB_OFF    4101
#define OUT_PARTIAL_OFF 4104
#define OUT_PARTIAL2_OFF (OUT_PARTIAL_OFF + NSPLIT * H)

// ---------------------------------------------------------------------------
// Kernel A v3: split-K column reduction of hidden @ (w + alpha*hebb).
// grid = 512, block = 512 -> 2 blocks/CU x 8 waves = 16 waves/CU (VGPR<=128
// forced by __launch_bounds__(512,4)). Block b owns rows [b*8, b*8+8) x the
// FULL row (512 threads x 2 vf4 cols = 4096 cols) -> per-instruction wave
// access is 1KB contiguous, per-block sweep fully contiguous.
// Each thread: 12 explicit vf4 loads batched into named locals per 2-row
// group (2 rows x 2 cols x 3 arrays) -> ~48 VGPRs of loads in flight, 2
// independent accumulators. Theory: R1/R2 showed kA is limited by
// outstanding-loads-per-wave (VGPR=36 capped MLP), not wave count alone.
// All loads cache-retaining: read set w+alpha+hebb = 201 MB < 256 MB L3.
// ---------------------------------------------------------------------------
__global__ __launch_bounds__(512, 4) void kA(const float* __restrict__ hidden,
                                             const float* __restrict__ w,
                                             const float* __restrict__ alpha,
                                             const float* __restrict__ hebb,
                                             float* __restrict__ partial) {
    const int t = threadIdx.x;                 // 0..511
    const int b = blockIdx.x;                  // 0..511
    const int r0 = b * ROWS_PER_SPLIT;
    const vf4* __restrict__ w4 = (const vf4*)w;
    const vf4* __restrict__ a4 = (const vf4*)alpha;
    const vf4* __restrict__ b4 = (const vf4*)hebb;

    vf4 acc0 = (vf4)(0.f);
    vf4 acc1 = (vf4)(0.f);

#pragma unroll
    for (int rr = 0; rr < ROWS_PER_SPLIT; rr += 2) {
        const int i0 = r0 + rr;
        const int i1 = i0 + 1;
        const float h0 = hidden[i0];           // wave-uniform -> scalar load
        const float h1 = hidden[i1];
        const int base0 = i0 * H4 + t;
        const int base1 = i1 * H4 + t;
        // 12 independent vf4 loads issued before any consumer:
        const vf4 w00 = w4[base0];
        const vf4 w01 = w4[base0 + 512];
        const vf4 a00 = a4[base0];
        const vf4 a01 = a4[base0 + 512];
        const vf4 b00 = b4[base0];
        const vf4 b01 = b4[base0 + 512];
        const vf4 w10 = w4[base1];
        const vf4 w11 = w4[base1 + 512];
        const vf4 a10 = a4[base1];
        const vf4 a11 = a4[base1 + 512];
        const vf4 b10 = b4[base1];
        const vf4 b11 = b4[base1 + 512];
        acc0 += h0 * (w00 + a00 * b00);
        acc1 += h0 * (w01 + a01 * b01);
        acc0 += h1 * (w10 + a10 * b10);
        acc1 += h1 * (w11 + a11 * b11);
    }
    vf4* __restrict__ p4 = (vf4*)partial;
    p4[b * H4 + t] = acc0;
    p4[b * H4 + t + 512] = acc1;
}

// ---------------------------------------------------------------------------
// Kernel B1: reduce 512 partials -> 32 partials. grid = (4, 32), block = 256.
// ---------------------------------------------------------------------------
__global__ __launch_bounds__(256) void kB1(const float* __restrict__ partial,
                                           float* __restrict__ partial2) {
    const int j4 = blockIdx.x * 256 + threadIdx.x;      // 0..1023
    const vf4* __restrict__ p4 = (const vf4*)partial;
    vf4 acc = (vf4)(0.f);
#pragma unroll
    for (int s = 0; s < NSPLIT / NSPLIT2; ++s) {        // 16
        acc += p4[(blockIdx.y * (NSPLIT / NSPLIT2) + s) * H4 + j4];
    }
    ((vf4*)partial2)[blockIdx.y * H4 + j4] = acc;
}

// ---------------------------------------------------------------------------
// Kernel B2: finish reduction + x@Wi + bi, tanh -> hactiv. grid = 16, block=256.
// ---------------------------------------------------------------------------
__global__ __launch_bounds__(256) void kB2(const float* __restrict__ x,
                                           const float* __restrict__ Wi,
                                           const float* __restrict__ bi,
                                           const float* __restrict__ partial2,
                                           float* __restrict__ hactiv) {
    const int j = blockIdx.x * 256 + threadIdx.x;       // 0..4095
    float s = bi[j];
#pragma unroll
    for (int k = 0; k < NIN; ++k) s += x[k] * Wi[k * H + j];
#pragma unroll
    for (int sp = 0; sp < NSPLIT2; ++sp) s += partial2[sp * H + j];
    hactiv[j] = tanhf(s);
}

// ---------------------------------------------------------------------------
// Kernel C: hebb_new = (1-eta)*hebb + eta*outer(hidden, hactiv)
// grid = H+1 = 4097 blocks, block = 256: block i owns ROW i (4096 contiguous
// elements) -> hidden[i] is a single scalar load; 16 fully-unrolled coalesced
// dword load/store pairs per thread (256B/wave/instr both directions).
// hebb load cache-retaining (L3-resident from kA); hebb_out store NT
// (write-once, never read -> don't evict the read set from L3).
// Heads (softmax policy + value) in the final extra block.
// ---------------------------------------------------------------------------
__global__ __launch_bounds__(256) void kC(const float* __restrict__ hebb,
                                          const float* __restrict__ hidden,
                                          const float* __restrict__ eta_p,
                                          const float* __restrict__ Wo,
                                          const float* __restrict__ bo,
                                          const float* __restrict__ Wv,
                                          const float* __restrict__ bv,
                                          float* __restrict__ out) {
    const float* __restrict__ hactiv = out + OUT_HACTIV_OFF;
    float* __restrict__ hebb_out = out + OUT_HEBB_OFF;

    if (blockIdx.x < (unsigned)H) {
        const unsigned i = blockIdx.x;               // row, uniform per block
        const unsigned base = i << 12;
        const float eta = eta_p[0];
        const float em = 1.f - eta;
        const float eh = eta * hidden[i];
#pragma unroll
        for (int k = 0; k < 16; ++k) {
            const unsigned c = (unsigned)(k * 256) + threadIdx.x;
            const float hb = hebb[base + c];
            const float v = em * hb + eh * hactiv[c];
            __builtin_nontemporal_store(v, &hebb_out[base + c]);
        }
    } else {
        __shared__ float red[5][256];
        float a0 = 0.f, a1 = 0.f, a2 = 0.f, a3 = 0.f, av = 0.f;
        const vf4* __restrict__ Wo4 = (const vf4*)Wo;
        for (int i = threadIdx.x; i < H; i += 256) {
            const float h = hactiv[i];
            const vf4 wo = Wo4[i];
            a0 += h * wo.x;
            a1 += h * wo.y;
            a2 += h * wo.z;
            a3 += h * wo.w;
            av += h * Wv[i];
        }
        red[0][threadIdx.x] = a0;
        red[1][threadIdx.x] = a1;
        red[2][threadIdx.x] = a2;
        red[3][threadIdx.x] = a3;
        red[4][threadIdx.x] = av;
        __syncthreads();
        for (int s = 128; s > 0; s >>= 1) {
            if ((int)threadIdx.x < s) {
#pragma unroll
                for (int k = 0; k < 5; ++k)
                    red[k][threadIdx.x] += red[k][threadIdx.x + s];
            }
            __syncthreads();
        }
        if (threadIdx.x == 0) {
            const float z0 = red[0][0] + bo[0];
            const float z1 = red[1][0] + bo[1];
            const float z2 = red[2][0] + bo[2];
            const float z3 = red[3][0] + bo[3];
            const float m = fmaxf(fmaxf(z0, z1), fmaxf(z2, z3));
            const float e0 = expf(z0 - m);
            const float e1 = expf(z1 - m);
            const float e2 = expf(z2 - m);
            const float e3 = expf(z3 - m);
            const float inv = 1.f / (e0 + e1 + e2 + e3);
            out[0] = e0 * inv;
            out[1] = e1 * inv;
            out[2] = e2 * inv;
            out[3] = e3 * inv;
            out[4] = red[4][0] + bv[0];
        }
    }
}

extern "C" void kernel_launch(void* const* d_in, const int* in_sizes, int n_in,
                              void* d_out, int out_size, void* d_ws, size_t ws_size,
                              hipStream_t stream) {
    const float* x      = (const float*)d_in[0];
    const float* hidden = (const float*)d_in[1];
    const float* hebb   = (const float*)d_in[2];
    const float* Wi     = (const float*)d_in[3];
    const float* bi     = (const float*)d_in[4];
    const float* w      = (const float*)d_in[5];
    const float* alpha  = (const float*)d_in[6];
    const float* eta    = (const float*)d_in[7];
    const float* Wo     = (const float*)d_in[8];
    const float* bo     = (const float*)d_in[9];
    const float* Wv     = (const float*)d_in[10];
    const float* bv     = (const float*)d_in[11];
    float* out = (float*)d_out;

    float* partial  = out + OUT_PARTIAL_OFF;
    float* partial2 = out + OUT_PARTIAL2_OFF;
    float* hactiv   = out + OUT_HACTIV_OFF;

    kA<<<NSPLIT, 512, 0, stream>>>(hidden, w, alpha, hebb, partial);
    kB1<<<dim3(4, NSPLIT2), 256, 0, stream>>>(partial, partial2);
    kB2<<<16, 256, 0, stream>>>(x, Wi, bi, partial2, hactiv);
    kC<<<H + 1, 256, 0, stream>>>(hebb, hidden, eta, Wo, bo, Wv, bv, out);
}

// Round 5
// 255.380 us; speedup vs baseline: 1.0548x; 1.0548x over previous
//
#include <hip/hip_runtime.h>
#include <math.h>

#define H 4096
#define NIN 17
#define H4 (H / 4)                    // 1024
#define NSPLIT 512
#define ROWS_PER_SPLIT (H / NSPLIT)   // 8

typedef float vf4 __attribute__((ext_vector_type(4)));

// d_out layout (fp32): [activout(4), valueout(1), hactiv(4096), hebb_new(4096*4096)]
//   hactiv at element offset 5; hebb at element offset 4101 (4B aligned only).
// Scratch lives inside the hebb output region (overwritten by kC afterwards):
//   partial at 4104 (byte 16416, 16B aligned): NSPLIT x H floats (8 MB)
#define OUT_HACTIV_OFF  5
#define OUT_HEBB_OFF    4101
#define OUT_PARTIAL_OFF 4104

// ---------------------------------------------------------------------------
// Kernel A — EXACT revert to the round-1 measured winner (54.4 us, 2.0 TB/s
// HBM, occ 17%). grid = 512, block = 256. Block b owns rows [b*8, b*8+8):
// 3 x 128 KB fully contiguous per block. Thread t's columns are fixed
// {t, t+256, t+512, t+768} (vf4 granularity) -> 4 vf4 accumulators.
// NT loads on w/alpha only; hebb + partial stay cache-retaining.
// R2 (col-split, occ 47%) and R3 (512-thr batched loads) both REGRESSED
// (73.7 / 77.0 us, VGPR stuck at 36 -> compiler sinks loads regardless);
// do not touch this kernel again without new counter evidence.
// ---------------------------------------------------------------------------
__global__ __launch_bounds__(256, 2) void kA(const float* __restrict__ hidden,
                                             const float* __restrict__ w,
                                             const float* __restrict__ alpha,
                                             const float* __restrict__ hebb,
                                             float* __restrict__ partial) {
    const int t = threadIdx.x;
    const int b = blockIdx.x;
    const int r0 = b * ROWS_PER_SPLIT;
    const vf4* __restrict__ w4 = (const vf4*)w;
    const vf4* __restrict__ a4 = (const vf4*)alpha;
    const vf4* __restrict__ b4 = (const vf4*)hebb;

    vf4 acc[4];
#pragma unroll
    for (int k = 0; k < 4; ++k) acc[k] = (vf4)(0.f);

#pragma unroll 2
    for (int r = 0; r < ROWS_PER_SPLIT; ++r) {
        const int i = r0 + r;
        const float hv = hidden[i];                 // wave-uniform -> scalar load
        const int rowbase = i * H4;
#pragma unroll
        for (int k = 0; k < 4; ++k) {
            const int idx = rowbase + t + k * 256;
            const vf4 wv = __builtin_nontemporal_load(&w4[idx]);
            const vf4 av = __builtin_nontemporal_load(&a4[idx]);
            const vf4 bv = b4[idx];                 // cache-retaining (kC re-reads)
            acc[k] += hv * (wv + av * bv);
        }
    }
    vf4* __restrict__ p4 = (vf4*)partial;
#pragma unroll
    for (int k = 0; k < 4; ++k)
        p4[(b << 10) + t + k * 256] = acc[k];
}

// ---------------------------------------------------------------------------
// Kernel B (fused B1+B2): full 512-split reduction + x@Wi + bi + tanh in ONE
// launch (was two; removes one inter-kernel gap + the partial2 round trip).
// grid = 64, block = 256. Block q owns 64 columns [q*64, +64).
// Thread t: col j = q*64 + (t&63), split-quarter sq = t>>6 -> 128 splits.
// Reads partial[s][j]: 64 consecutive dwords = 256B contiguous per instr.
// LDS combine over the 4 quarters, then lanes 0..63 finish Wi matvec + tanh.
// ---------------------------------------------------------------------------
__global__ __launch_bounds__(256) void kB(const float* __restrict__ x,
                                          const float* __restrict__ Wi,
                                          const float* __restrict__ bi,
                                          const float* __restrict__ partial,
                                          float* __restrict__ hactiv) {
    const int t = threadIdx.x;
    const int j = blockIdx.x * 64 + (t & 63);        // column 0..4095
    const int sq = t >> 6;                           // split quarter 0..3
    float acc = 0.f;
#pragma unroll 8
    for (int s = sq * 128; s < sq * 128 + 128; ++s)
        acc += partial[s * H + j];

    __shared__ float red[4][64];
    red[sq][t & 63] = acc;
    __syncthreads();
    if (t < 64) {
        float s = red[0][t] + red[1][t] + red[2][t] + red[3][t] + bi[j];
#pragma unroll
        for (int k = 0; k < NIN; ++k) s += x[k] * Wi[k * H + j];
        hactiv[j] = tanhf(s);
    }
}

// ---------------------------------------------------------------------------
// Kernel C: hebb_new = (1-eta)*hebb + eta*outer(hidden, hactiv)
// grid = 2048+1, block = 512. Block b owns rows {2b, 2b+1} = 8192 contiguous
// elements. Per thread: 4 independent vf4 hebb loads (aligned, 2KB/wave/instr)
// -> real MLP; hactiv read as scalar dwords (16KB, L2-hot broadcast); stores
// are NT scalar dwords (hebb_out base only 4B-aligned), coalesced.
// Row index uniform per k: row = 2b + (k>>1). Heads in final extra block.
// ---------------------------------------------------------------------------
__global__ __launch_bounds__(512) void kC(const float* __restrict__ hebb,
                                          const float* __restrict__ hidden,
                                          const float* __restrict__ eta_p,
                                          const float* __restrict__ Wo,
                                          const float* __restrict__ bo,
                                          const float* __restrict__ Wv,
                                          const float* __restrict__ bv,
                                          float* __restrict__ out) {
    const float* __restrict__ hactiv = out + OUT_HACTIV_OFF;
    float* __restrict__ hebb_out = out + OUT_HEBB_OFF;
    const int t = threadIdx.x;

    if (blockIdx.x < (unsigned)(H / 2)) {
        const unsigned b = blockIdx.x;
        const float eta = eta_p[0];
        const float em = 1.f - eta;
        const float eh0 = eta * hidden[2 * b];
        const float eh1 = eta * hidden[2 * b + 1];
        const vf4* __restrict__ hb4 = (const vf4*)hebb;

        // 4 independent vf4 loads in flight before any consumer.
        vf4 hb[4];
        unsigned g4[4];
#pragma unroll
        for (int k = 0; k < 4; ++k) {
            g4[k] = b * 2048u + (unsigned)(k * 512) + t;   // vf4 index
            hb[k] = hb4[g4[k]];
        }
#pragma unroll
        for (int k = 0; k < 4; ++k) {
            const unsigned col4 = g4[k] & 1023u;
            const float eh = (k < 2) ? eh0 : eh1;
            const float ha0 = hactiv[col4 * 4 + 0];
            const float ha1 = hactiv[col4 * 4 + 1];
            const float ha2 = hactiv[col4 * 4 + 2];
            const float ha3 = hactiv[col4 * 4 + 3];
            const unsigned e = g4[k] * 4u;
            __builtin_nontemporal_store(em * hb[k].x + eh * ha0, &hebb_out[e + 0]);
            __builtin_nontemporal_store(em * hb[k].y + eh * ha1, &hebb_out[e + 1]);
            __builtin_nontemporal_store(em * hb[k].z + eh * ha2, &hebb_out[e + 2]);
            __builtin_nontemporal_store(em * hb[k].w + eh * ha3, &hebb_out[e + 3]);
        }
    } else {
        __shared__ float red[5][512];
        float a0 = 0.f, a1 = 0.f, a2 = 0.f, a3 = 0.f, av = 0.f;
        const vf4* __restrict__ Wo4 = (const vf4*)Wo;
        for (int i = t; i < H; i += 512) {
            const float h = hactiv[i];
            const vf4 wo = Wo4[i];
            a0 += h * wo.x;
            a1 += h * wo.y;
            a2 += h * wo.z;
            a3 += h * wo.w;
            av += h * Wv[i];
        }
        red[0][t] = a0;
        red[1][t] = a1;
        red[2][t] = a2;
        red[3][t] = a3;
        red[4][t] = av;
        __syncthreads();
        for (int s = 256; s > 0; s >>= 1) {
            if (t < s) {
#pragma unroll
                for (int k = 0; k < 5; ++k)
                    red[k][t] += red[k][t + s];
            }
            __syncthreads();
        }
        if (t == 0) {
            const float z0 = red[0][0] + bo[0];
            const float z1 = red[1][0] + bo[1];
            const float z2 = red[2][0] + bo[2];
            const float z3 = red[3][0] + bo[3];
            const float m = fmaxf(fmaxf(z0, z1), fmaxf(z2, z3));
            const float e0 = expf(z0 - m);
            const float e1 = expf(z1 - m);
            const float e2 = expf(z2 - m);
            const float e3 = expf(z3 - m);
            const float inv = 1.f / (e0 + e1 + e2 + e3);
            out[0] = e0 * inv;
            out[1] = e1 * inv;
            out[2] = e2 * inv;
            out[3] = e3 * inv;
            out[4] = red[4][0] + bv[0];
        }
    }
}

extern "C" void kernel_launch(void* const* d_in, const int* in_sizes, int n_in,
                              void* d_out, int out_size, void* d_ws, size_t ws_size,
                              hipStream_t stream) {
    const float* x      = (const float*)d_in[0];
    const float* hidden = (const float*)d_in[1];
    const float* hebb   = (const float*)d_in[2];
    const float* Wi     = (const float*)d_in[3];
    const float* bi     = (const float*)d_in[4];
    const float* w      = (const float*)d_in[5];
    const float* alpha  = (const float*)d_in[6];
    const float* eta    = (const float*)d_in[7];
    const float* Wo     = (const float*)d_in[8];
    const float* bo     = (const float*)d_in[9];
    const float* Wv     = (const float*)d_in[10];
    const float* bv     = (const float*)d_in[11];
    float* out = (float*)d_out;

    float* partial = out + OUT_PARTIAL_OFF;
    float* hactiv  = out + OUT_HACTIV_OFF;

    kA<<<NSPLIT, 256, 0, stream>>>(hidden, w, alpha, hebb, partial);
    kB<<<64, 256, 0, stream>>>(x, Wi, bi, partial, hactiv);
    kC<<<H / 2 + 1, 512, 0, stream>>>(hebb, hidden, eta, Wo, bo, Wv, bv, out);
}